// Round 1
// baseline (18.596 us; speedup 1.0000x reference)
//
#include <hip/hip_runtime.h>

#define NB 4
#define NGRID 512
#define NTARGET 512
#define NBASIS 8
#define NCH 8
#define TT 4                    // targets per block
#define WAVES 4
#define GCHUNK (NGRID / WAVES)  // 128 g-iterations per wave

#if defined(__has_builtin)
#if __has_builtin(__builtin_amdgcn_exp2f)
#define EXP2F(x) __builtin_amdgcn_exp2f(x)
#else
#define EXP2F(x) exp2f(x)
#endif
#else
#define EXP2F(x) exp2f(x)
#endif

__global__ __launch_bounds__(WAVES * 64) void final_layer_kernel(
    const float* __restrict__ x_grid,    // (B, G, C)
    const float* __restrict__ h_grid,    // (B, G, K, C)
    const float* __restrict__ target_x,  // (B, T, C)
    const float* __restrict__ W,         // (1, K)
    const float* __restrict__ bias,      // (1,)
    const float* __restrict__ sigma,     // (K, C)
    float* __restrict__ out)             // (B, T, C)
{
    __shared__ float lds[WAVES * TT * NCH];   // 512 B

    const int tid = threadIdx.x;
    const int l   = tid & 63;    // lane
    const int w   = tid >> 6;    // wave id
    const int k   = l >> 3;      // basis index
    const int c   = l & 7;       // channel index

    const int bi = blockIdx.x;
    const int b  = bi >> 7;            // T/TT = 128 tiles per batch
    const int t0 = (bi & 127) * TT;

    // per-(k,c): coef2 = -0.5 * log2(e) / scale^2,  scale = exp(sigma)+eps
    const float LOG2E = 1.4426950408889634f;
    float sg    = sigma[l];
    float scale = __expf(sg) + 1e-6f;
    float coef2 = -0.5f * LOG2E / (scale * scale);

    float wk = W[k];

    float tx[TT], acc[TT];
#pragma unroll
    for (int t = 0; t < TT; ++t) {
        tx[t]  = target_x[((size_t)b * NTARGET + (t0 + t)) * NCH + c];
        acc[t] = 0.0f;
    }

    const int g0 = w * GCHUNK;
    const float* hg = h_grid + ((size_t)b * NGRID + g0) * (NBASIS * NCH) + l;
    const float* xp = x_grid + ((size_t)b * NGRID + g0) * NCH + c;

#pragma unroll 4
    for (int g = 0; g < GCHUNK; ++g) {
        float hv = hg[(size_t)g * (NBASIS * NCH)];  // coalesced: lane l offset
        float xg = xp[(size_t)g * NCH];             // 8 distinct addrs, broadcast
#pragma unroll
        for (int t = 0; t < TT; ++t) {
            float d = xg - tx[t];
            float e = EXP2F(coef2 * d * d);
            acc[t] = fmaf(hv, e, acc[t]);
        }
    }

    // fold W[k], then butterfly-reduce over k (lane bits 3..5)
#pragma unroll
    for (int t = 0; t < TT; ++t) {
        float v = acc[t] * wk;
        v += __shfl_xor(v, 8);
        v += __shfl_xor(v, 16);
        v += __shfl_xor(v, 32);
        acc[t] = v;
    }

    if (k == 0) {
#pragma unroll
        for (int t = 0; t < TT; ++t)
            lds[(w * TT + t) * NCH + c] = acc[t];
    }
    __syncthreads();

    // cross-wave reduce + bias + store: 32 outputs per block
    if (tid < TT * NCH) {
        float v = 0.0f;
#pragma unroll
        for (int ww = 0; ww < WAVES; ++ww)
            v += lds[ww * TT * NCH + tid];
        v += bias[0];
        int t  = tid >> 3;
        int cc = tid & 7;
        out[((size_t)b * NTARGET + (t0 + t)) * NCH + cc] = v;
    }
}

extern "C" void kernel_launch(void* const* d_in, const int* in_sizes, int n_in,
                              void* d_out, int out_size, void* d_ws, size_t ws_size,
                              hipStream_t stream) {
    const float* x_grid   = (const float*)d_in[0];
    const float* h_grid   = (const float*)d_in[1];
    const float* target_x = (const float*)d_in[2];
    const float* W        = (const float*)d_in[3];
    const float* bias     = (const float*)d_in[4];
    const float* sigma    = (const float*)d_in[5];
    float* out = (float*)d_out;

    dim3 grid(NB * (NTARGET / TT));  // 512 blocks
    dim3 block(WAVES * 64);          // 256 threads
    final_layer_kernel<<<grid, block, 0, stream>>>(x_grid, h_grid, target_x,
                                                   W, bias, sigma, out);
}

// Round 2
// 16.553 us; speedup vs baseline: 1.1234x; 1.1234x over previous
//
#include <hip/hip_runtime.h>

#define NB 4
#define NGRID 512
#define NTARGET 512
#define NBASIS 8
#define NCH 8
#define TT 4                    // targets per block
#define WAVES 8
#define GCHUNK (NGRID / WAVES)  // 64 g-iterations per wave

#if defined(__has_builtin)
#if __has_builtin(__builtin_amdgcn_exp2f)
#define EXP2F(x) __builtin_amdgcn_exp2f(x)
#else
#define EXP2F(x) exp2f(x)
#endif
#else
#define EXP2F(x) exp2f(x)
#endif

__global__ __launch_bounds__(WAVES * 64) void final_layer_kernel(
    const float* __restrict__ x_grid,    // (B, G, C)
    const float* __restrict__ h_grid,    // (B, G, K, C)
    const float* __restrict__ target_x,  // (B, T, C)
    const float* __restrict__ W,         // (1, K)
    const float* __restrict__ bias,      // (1,)
    const float* __restrict__ sigma,     // (K, C)
    float* __restrict__ out)             // (B, T, C)
{
    __shared__ float lds[WAVES * TT * NCH];   // 1 KB

    const int tid = threadIdx.x;
    const int l   = tid & 63;    // lane
    const int w   = tid >> 6;    // wave id (0..7)
    const int k   = l >> 3;      // basis index
    const int c   = l & 7;       // channel index

    const int bi = blockIdx.x;
    const int b  = bi >> 7;            // T/TT = 128 tiles per batch
    const int t0 = (bi & 127) * TT;

    // per-(k,c): coef2 = -0.5 * log2(e) / scale^2,  scale = exp(sigma)+eps
    const float LOG2E = 1.4426950408889634f;
    float sg    = sigma[l];
    float scale = __expf(sg) + 1e-6f;
    float coef2 = -0.5f * LOG2E / (scale * scale);

    float wk = W[k];

    // expand coef2*(xg - tx)^2 = coef2*xg^2 + B_t*xg + A_t
    float A[TT], Bc[TT], acc[TT];
#pragma unroll
    for (int t = 0; t < TT; ++t) {
        float tx = target_x[((size_t)b * NTARGET + (t0 + t)) * NCH + c];
        Bc[t]  = -2.0f * coef2 * tx;
        A[t]   = coef2 * tx * tx;
        acc[t] = 0.0f;
    }

    const int g0 = w * GCHUNK;
    const float* hg = h_grid + ((size_t)b * NGRID + g0) * (NBASIS * NCH) + l;
    const float* xp = x_grid + ((size_t)b * NGRID + g0) * NCH + c;

#pragma unroll 8
    for (int g = 0; g < GCHUNK; ++g) {
        float hv = hg[(size_t)g * (NBASIS * NCH)];  // coalesced dword/lane
        float xg = xp[(size_t)g * NCH];             // 8 distinct addrs, broadcast
        float q  = coef2 * xg;
        float p  = q * xg;                          // shared across targets
#pragma unroll
        for (int t = 0; t < TT; ++t) {
            float arg = fmaf(Bc[t], xg, p + A[t]);
            float e   = EXP2F(arg);
            acc[t] = fmaf(hv, e, acc[t]);
        }
    }

    // fold W[k], then butterfly-reduce over k (lane bits 3..5)
#pragma unroll
    for (int t = 0; t < TT; ++t) {
        float v = acc[t] * wk;
        v += __shfl_xor(v, 8);
        v += __shfl_xor(v, 16);
        v += __shfl_xor(v, 32);
        acc[t] = v;
    }

    if (k == 0) {
#pragma unroll
        for (int t = 0; t < TT; ++t)
            lds[(w * TT + t) * NCH + c] = acc[t];
    }
    __syncthreads();

    // cross-wave reduce + bias + store: 32 outputs per block
    if (tid < TT * NCH) {
        float v = 0.0f;
#pragma unroll
        for (int ww = 0; ww < WAVES; ++ww)
            v += lds[ww * TT * NCH + tid];
        v += bias[0];
        int t  = tid >> 3;
        int cc = tid & 7;
        out[((size_t)b * NTARGET + (t0 + t)) * NCH + cc] = v;
    }
}

extern "C" void kernel_launch(void* const* d_in, const int* in_sizes, int n_in,
                              void* d_out, int out_size, void* d_ws, size_t ws_size,
                              hipStream_t stream) {
    const float* x_grid   = (const float*)d_in[0];
    const float* h_grid   = (const float*)d_in[1];
    const float* target_x = (const float*)d_in[2];
    const float* W        = (const float*)d_in[3];
    const float* bias     = (const float*)d_in[4];
    const float* sigma    = (const float*)d_in[5];
    float* out = (float*)d_out;

    dim3 grid(NB * (NTARGET / TT));  // 512 blocks
    dim3 block(WAVES * 64);          // 512 threads = 8 waves
    final_layer_kernel<<<grid, block, 0, stream>>>(x_grid, h_grid, target_x,
                                                   W, bias, sigma, out);
}